// Round 6
// baseline (83.493 us; speedup 1.0000x reference)
//
#include <hip/hip_runtime.h>

// 4-qubit statevector QNN. Two samples per thread, element-wise packed into
// float2 ext-vectors so the whole circuit lowers to v_pk_{fma,mul,add}_f32
// (dual-FP32 packed ops, 2x per-instruction throughput). Layer-0 RY fused
// into initial angles; layer-2 RY folded into <Z>. HW trig in revolutions.
// Output: 12 contiguous floats/thread = 3 aligned float4 stores.

#define INV_2PI 0.15915494309189535f

typedef float v2f __attribute__((ext_vector_type(2)));

static __device__ __forceinline__ v2f v2(float x) { v2f r; r.x = x; r.y = x; return r; }
static __device__ __forceinline__ v2f vfma(v2f a, v2f b, v2f c) {
    return __builtin_elementwise_fma(a, b, c);
}

// RY with wave-uniform scalar angle (weights): c,s splatted.
template <int MASK>
__device__ __forceinline__ void apply_ry(v2f st[16], float cs, float ss) {
    const v2f c = v2(cs), s = v2(ss);
#pragma unroll
    for (int i = 0; i < 16; ++i) {
        if (!(i & MASK)) {
            v2f a0 = st[i];
            v2f a1 = st[i | MASK];
            st[i]        = vfma(c, a0, -(s * a1));
            st[i | MASK] = vfma(s, a0,  c * a1);
        }
    }
}

template <int CMASK, int TMASK>
__device__ __forceinline__ void apply_cnot(v2f st[16]) {
#pragma unroll
    for (int i = 0; i < 16; ++i) {
        if ((i & CMASK) && !(i & TMASK)) {
            v2f tmp       = st[i];
            st[i]         = st[i | TMASK];
            st[i | TMASK] = tmp;
        }
    }
}

__global__ __launch_bounds__(256) void qnn_kernel(
    const float* __restrict__ x,      // (B,4)
    const float* __restrict__ qw,     // (3,4)
    const float* __restrict__ W,      // (6,4)
    const float* __restrict__ bias,   // (6,)
    float* __restrict__ out,          // (B,6)
    int B)
{
    __shared__ float qw0[4], c1h[4], s1h[4], c2f[4], s2f[4], sW[24], sb[6];

    const int tid = threadIdx.x;
    if (tid < 4) {
        qw0[tid] = qw[tid];
        float r1 = qw[4 + tid] * (0.5f * INV_2PI);
        c1h[tid] = __builtin_amdgcn_cosf(r1);
        s1h[tid] = __builtin_amdgcn_sinf(r1);
        float r2 = qw[8 + tid] * INV_2PI;
        c2f[tid] = __builtin_amdgcn_cosf(r2);
        s2f[tid] = __builtin_amdgcn_sinf(r2);
    }
    if (tid < 24) sW[tid] = W[tid];
    if (tid < 6)  sb[tid] = bias[tid];
    __syncthreads();

    const size_t t  = (size_t)blockIdx.x * 256u + (size_t)tid;
    const size_t s0 = 2u * t;
    if (s0 >= (size_t)B) return;

    const float4* x4 = reinterpret_cast<const float4*>(x);
    const bool paired = (s0 + 1 < (size_t)B);
    float4 xa = x4[s0];
    float4 xb = paired ? x4[s0 + 1] : xa;

    // Packed fused initial angles: lane .x = sample s0, lane .y = sample s0+1
    v2f c0, s0v, c1, s1v, c2, s2v, c3, s3v;
    {
        v2f r0; r0.x = (xa.x + qw0[0]) * (0.5f * INV_2PI); r0.y = (xb.x + qw0[0]) * (0.5f * INV_2PI);
        v2f r1; r1.x = (xa.y + qw0[1]) * (0.5f * INV_2PI); r1.y = (xb.y + qw0[1]) * (0.5f * INV_2PI);
        v2f r2; r2.x = (xa.z + qw0[2]) * (0.5f * INV_2PI); r2.y = (xb.z + qw0[2]) * (0.5f * INV_2PI);
        v2f r3; r3.x = (xa.w + qw0[3]) * (0.5f * INV_2PI); r3.y = (xb.w + qw0[3]) * (0.5f * INV_2PI);
        c0.x  = __builtin_amdgcn_cosf(r0.x); c0.y  = __builtin_amdgcn_cosf(r0.y);
        s0v.x = __builtin_amdgcn_sinf(r0.x); s0v.y = __builtin_amdgcn_sinf(r0.y);
        c1.x  = __builtin_amdgcn_cosf(r1.x); c1.y  = __builtin_amdgcn_cosf(r1.y);
        s1v.x = __builtin_amdgcn_sinf(r1.x); s1v.y = __builtin_amdgcn_sinf(r1.y);
        c2.x  = __builtin_amdgcn_cosf(r2.x); c2.y  = __builtin_amdgcn_cosf(r2.y);
        s2v.x = __builtin_amdgcn_sinf(r2.x); s2v.y = __builtin_amdgcn_sinf(r2.y);
        c3.x  = __builtin_amdgcn_cosf(r3.x); c3.y  = __builtin_amdgcn_cosf(r3.y);
        s3v.x = __builtin_amdgcn_sinf(r3.x); s3v.y = __builtin_amdgcn_sinf(r3.y);
    }

    v2f a01[4] = { c0 * c1, c0 * s1v, s0v * c1, s0v * s1v };  // bits 8,4
    v2f a23[4] = { c2 * c3, c2 * s3v, s2v * c3, s2v * s3v };  // bits 2,1

    v2f st[16];
#pragma unroll
    for (int hi = 0; hi < 4; ++hi)
#pragma unroll
        for (int lo = 0; lo < 4; ++lo)
            st[hi * 4 + lo] = a01[hi] * a23[lo];

    apply_cnot<8, 4>(st); apply_cnot<4, 2>(st);
    apply_cnot<2, 1>(st); apply_cnot<1, 8>(st);

    apply_ry<8>(st, c1h[0], s1h[0]);
    apply_ry<4>(st, c1h[1], s1h[1]);
    apply_ry<2>(st, c1h[2], s1h[2]);
    apply_ry<1>(st, c1h[3], s1h[3]);

    apply_cnot<8, 4>(st); apply_cnot<4, 2>(st);
    apply_cnot<2, 1>(st); apply_cnot<1, 8>(st);

    // Layer-2 RY folded into <Z_w>: z_w = c2f*(1-2*A1) - 2*s2f*X
    v2f p[16];
#pragma unroll
    for (int i = 0; i < 16; ++i) p[i] = st[i] * st[i];

    v2f z[4];
#pragma unroll
    for (int w = 0; w < 4; ++w) {
        const int m = 8 >> w;
        v2f A1 = v2(0.0f), X = v2(0.0f);
#pragma unroll
        for (int i = 0; i < 16; ++i) {
            if (!(i & m)) {
                A1 += p[i | m];
                X = vfma(st[i], st[i | m], X);
            }
        }
        z[w] = vfma(v2(c2f[w]), vfma(v2(-2.0f), A1, v2(1.0f)), v2(-2.0f * s2f[w]) * X);
    }

    // logits + softmax (no max-subtraction; |logits| small)
    v2f e[6];
    v2f sum = v2(0.0f);
#pragma unroll
    for (int j = 0; j < 6; ++j) {
        v2f a = v2(sb[j]);
        a = vfma(z[0], v2(sW[j * 4 + 0]), a);
        a = vfma(z[1], v2(sW[j * 4 + 1]), a);
        a = vfma(z[2], v2(sW[j * 4 + 2]), a);
        a = vfma(z[3], v2(sW[j * 4 + 3]), a);
        e[j].x = __expf(a.x);
        e[j].y = __expf(a.y);
        sum += e[j];
    }
    v2f inv;
    inv.x = __builtin_amdgcn_rcpf(sum.x);
    inv.y = __builtin_amdgcn_rcpf(sum.y);
#pragma unroll
    for (int j = 0; j < 6; ++j) e[j] *= inv;

    float* op = out + s0 * 6u;    // s0 even -> 16B-aligned
    if (paired) {
        reinterpret_cast<float4*>(op)[0] = make_float4(e[0].x, e[1].x, e[2].x, e[3].x);
        reinterpret_cast<float4*>(op)[1] = make_float4(e[4].x, e[5].x, e[0].y, e[1].y);
        reinterpret_cast<float4*>(op)[2] = make_float4(e[2].y, e[3].y, e[4].y, e[5].y);
    } else {
#pragma unroll
        for (int j = 0; j < 6; ++j) op[j] = e[j].x;
    }
}

extern "C" void kernel_launch(void* const* d_in, const int* in_sizes, int n_in,
                              void* d_out, int out_size, void* d_ws, size_t ws_size,
                              hipStream_t stream) {
    const float* x    = (const float*)d_in[0];   // (B,4)
    const float* qw   = (const float*)d_in[1];   // (3,4)
    const float* W    = (const float*)d_in[2];   // (6,4)
    const float* bias = (const float*)d_in[3];   // (6,)
    float* out = (float*)d_out;

    const int B = in_sizes[0] / 4;
    const int threads = (B + 1) / 2;
    const int blocks = (threads + 255) / 256;
    qnn_kernel<<<blocks, 256, 0, stream>>>(x, qw, W, bias, out, B);
}

// Round 7
// 80.270 us; speedup vs baseline: 1.0402x; 1.0402x over previous
//
#include <hip/hip_runtime.h>

// 4-qubit statevector QNN, one thread = one sample. Best-measured variant
// (round 3, 81.9us): layer-0 RY fused into initial angles (same-axis rotations
// add); final RY layer folded into the <Z> extraction; HW trig in revolutions;
// LDS-staged coalesced float4 output.

#define INV_2PI 0.15915494309189535f

template <int MASK>
__device__ __forceinline__ void apply_ry(float st[16], float c, float s) {
#pragma unroll
    for (int i = 0; i < 16; ++i) {
        if (!(i & MASK)) {
            float a0 = st[i];
            float a1 = st[i | MASK];
            st[i]        = fmaf(c, a0, -s * a1);
            st[i | MASK] = fmaf(s, a0,  c * a1);
        }
    }
}

template <int CMASK, int TMASK>
__device__ __forceinline__ void apply_cnot(float st[16]) {
#pragma unroll
    for (int i = 0; i < 16; ++i) {
        if ((i & CMASK) && !(i & TMASK)) {
            float tmp     = st[i];
            st[i]         = st[i | TMASK];
            st[i | TMASK] = tmp;
        }
    }
}

__global__ __launch_bounds__(256) void qnn_kernel(
    const float* __restrict__ x,      // (B,4)
    const float* __restrict__ qw,     // (3,4)
    const float* __restrict__ W,      // (6,4)
    const float* __restrict__ bias,   // (6,)
    float* __restrict__ out,          // (B,6)
    int B)
{
    __shared__ float qw0[4];           // layer-0 raw angles (fused into x)
    __shared__ float c1h[4], s1h[4];   // layer-1 half-angle cos/sin
    __shared__ float c2f[4], s2f[4];   // layer-2 FULL-angle cos/sin (for fold)
    __shared__ float sW[24], sb[6];
    __shared__ float so[256 * 6];      // output staging

    const int tid = threadIdx.x;
    if (tid < 4) {
        qw0[tid] = qw[tid];
        float r1 = qw[4 + tid] * (0.5f * INV_2PI);
        c1h[tid] = __builtin_amdgcn_cosf(r1);
        s1h[tid] = __builtin_amdgcn_sinf(r1);
        float r2 = qw[8 + tid] * INV_2PI;
        c2f[tid] = __builtin_amdgcn_cosf(r2);
        s2f[tid] = __builtin_amdgcn_sinf(r2);
    }
    if (tid < 24) sW[tid] = W[tid];
    if (tid < 6)  sb[tid] = bias[tid];
    __syncthreads();

    const int b = blockIdx.x * 256 + tid;
    const bool valid = (b < B);

    float4 xv = valid ? reinterpret_cast<const float4*>(x)[b]
                      : make_float4(0.f, 0.f, 0.f, 0.f);

    // Fused initial product state: half-angles (x_k + w0_k)/2
    float c0, s0, c1, s1, c2, s2, c3, s3;
    {
        float r0 = (xv.x + qw0[0]) * (0.5f * INV_2PI);
        float r1 = (xv.y + qw0[1]) * (0.5f * INV_2PI);
        float r2 = (xv.z + qw0[2]) * (0.5f * INV_2PI);
        float r3 = (xv.w + qw0[3]) * (0.5f * INV_2PI);
        c0 = __builtin_amdgcn_cosf(r0); s0 = __builtin_amdgcn_sinf(r0);
        c1 = __builtin_amdgcn_cosf(r1); s1 = __builtin_amdgcn_sinf(r1);
        c2 = __builtin_amdgcn_cosf(r2); s2 = __builtin_amdgcn_sinf(r2);
        c3 = __builtin_amdgcn_cosf(r3); s3 = __builtin_amdgcn_sinf(r3);
    }

    float a01[4] = { c0 * c1, c0 * s1, s0 * c1, s0 * s1 };  // bits 8,4
    float a23[4] = { c2 * c3, c2 * s3, s2 * c3, s2 * s3 };  // bits 2,1

    float st[16];
#pragma unroll
    for (int hi = 0; hi < 4; ++hi)
#pragma unroll
        for (int lo = 0; lo < 4; ++lo)
            st[hi * 4 + lo] = a01[hi] * a23[lo];

    // CNOT ring (register renames), layer-1 RY, CNOT ring
    apply_cnot<8, 4>(st); apply_cnot<4, 2>(st);
    apply_cnot<2, 1>(st); apply_cnot<1, 8>(st);

    apply_ry<8>(st, c1h[0], s1h[0]);
    apply_ry<4>(st, c1h[1], s1h[1]);
    apply_ry<2>(st, c1h[2], s1h[2]);
    apply_ry<1>(st, c1h[3], s1h[3]);

    apply_cnot<8, 4>(st); apply_cnot<4, 2>(st);
    apply_cnot<2, 1>(st); apply_cnot<1, 8>(st);

    // Layer-2 RY folded into <Z_w>:
    // z_w = cos(th_w) * (1 - 2*A1_w) - 2*sin(th_w) * X_w
    float p[16];
#pragma unroll
    for (int i = 0; i < 16; ++i) p[i] = st[i] * st[i];

    float z[4];
#pragma unroll
    for (int w = 0; w < 4; ++w) {
        const int m = 8 >> w;
        float A1 = 0.0f, X = 0.0f;
#pragma unroll
        for (int i = 0; i < 16; ++i) {
            if (!(i & m)) {
                A1 += p[i | m];
                X  = fmaf(st[i], st[i | m], X);
            }
        }
        z[w] = fmaf(c2f[w], fmaf(-2.0f, A1, 1.0f), -2.0f * s2f[w] * X);
    }

    // logits + softmax (no max-subtraction; |logits| small)
    float e[6];
    float sum = 0.0f;
#pragma unroll
    for (int j = 0; j < 6; ++j) {
        float a = sb[j];
        a = fmaf(z[0], sW[j * 4 + 0], a);
        a = fmaf(z[1], sW[j * 4 + 1], a);
        a = fmaf(z[2], sW[j * 4 + 2], a);
        a = fmaf(z[3], sW[j * 4 + 3], a);
        e[j] = __expf(a);
        sum += e[j];
    }
    const float inv = __builtin_amdgcn_rcpf(sum);

    // Stage to LDS, then fully-coalesced float4 stores.
#pragma unroll
    for (int j = 0; j < 6; ++j) so[tid * 6 + j] = e[j] * inv;
    __syncthreads();

    const float4* so4 = reinterpret_cast<const float4*>(so);
    float4* out4 = reinterpret_cast<float4*>(out);
    const long long base = (long long)blockIdx.x * 384;   // 256*6/4
    const long long total4 = (long long)B * 6 / 4;        // B*6 divisible by 4
#pragma unroll
    for (int k = 0; k < 2; ++k) {
        int idx = tid + k * 256;
        if (idx < 384 && base + idx < total4)
            out4[base + idx] = so4[idx];
    }
}

extern "C" void kernel_launch(void* const* d_in, const int* in_sizes, int n_in,
                              void* d_out, int out_size, void* d_ws, size_t ws_size,
                              hipStream_t stream) {
    const float* x    = (const float*)d_in[0];   // (B,4)
    const float* qw   = (const float*)d_in[1];   // (3,4)
    const float* W    = (const float*)d_in[2];   // (6,4)
    const float* bias = (const float*)d_in[3];   // (6,)
    float* out = (float*)d_out;

    const int B = in_sizes[0] / 4;
    const int blocks = (B + 255) / 256;
    qnn_kernel<<<blocks, 256, 0, stream>>>(x, qw, W, bias, out, B);
}